// Round 8
// baseline (223.425 us; speedup 1.0000x reference)
//
#include <hip/hip_runtime.h>
#include <hip/hip_bf16.h>
#include <math.h>

#define NCLS 10
#define NTOT 8192
#define NTIL 64        // 128-row panels per side
#define NBLKS 544      // sum_{it} (16 - it/4) strip blocks = 8*68
#define NS 64          // partial slots per row (packed col+row ranges)

using short8 = __attribute__((ext_vector_type(8))) short;
using f32x4  = __attribute__((ext_vector_type(4))) float;

__device__ __forceinline__ float digammaf_dev(float x) {
    float r = 0.0f;
    while (x < 6.0f) { r -= 1.0f / x; x += 1.0f; }
    float inv = 1.0f / x;
    float inv2 = inv * inv;
    float s = logf(x) - 0.5f * inv
            - inv2 * (0.083333333333f - inv2 * (0.0083333333333f - inv2 * 0.0039682539683f));
    return r + s;
}

__device__ __forceinline__ void cmpswap(float& a, float& b) {
    float lo = fminf(a, b), hi = fmaxf(a, b);
    a = lo; b = hi;
}

// branchless insert of v into ascending quad, keep 4 smallest
__device__ __forceinline__ void ins7(float v, float& b0, float& b1, float& b2, float& b3) {
    float x0 = fminf(b0, v); float c0 = fmaxf(b0, v);
    float x1 = fminf(b1, c0); float c1 = fmaxf(b1, c0);
    float x2 = fminf(b2, c1); float c2 = fmaxf(b2, c1);
    float x3 = fminf(b3, c2);
    b0 = x0; b1 = x1; b2 = x2; b3 = x3;
}

// merge my sorted quad with lane^mk's sorted quad -> 4 smallest of union, sorted
__device__ __forceinline__ void bmerge(int mk, float& v0, float& v1, float& v2, float& v3) {
    float u0 = __shfl_xor(v0, mk), u1 = __shfl_xor(v1, mk);
    float u2 = __shfl_xor(v2, mk), u3 = __shfl_xor(v3, mk);
    float m0 = fminf(v0, u3), m1 = fminf(v1, u2);
    float m2 = fminf(v2, u1), m3 = fminf(v3, u0);
    cmpswap(m0, m2); cmpswap(m1, m3);
    cmpswap(m0, m1); cmpswap(m2, m3);
    v0 = m0; v1 = m1; v2 = m2; v3 = m3;
}

__device__ __forceinline__ void gload_lds16(const void* g, void* s) {
    __builtin_amdgcn_global_load_lds((const __attribute__((address_space(1))) void*)g,
                                     (__attribute__((address_space(3))) void*)s, 16, 0, 0);
}

__global__ void zero_kernel(int* cls) {
    if (threadIdx.x < 16) cls[threadIdx.x] = 0;
}

// per row: sq (fp32), XS[row][0..127]=hi(bf16), [128..255]=lo(bf16)
__global__ void prep_kernel(const float* __restrict__ X,
                            float* __restrict__ sq, unsigned short* __restrict__ XS) {
    int wave = threadIdx.x >> 6, lane = threadIdx.x & 63;
    int row = blockIdx.x * 4 + wave;
    float2 v = *(const float2*)(X + (size_t)row * 128 + lane * 2);
    __hip_bfloat16 h0 = __float2bfloat16(v.x);
    __hip_bfloat16 h1 = __float2bfloat16(v.y);
    float hf0 = __bfloat162float(h0), hf1 = __bfloat162float(h1);
    __hip_bfloat16 l0 = __float2bfloat16(v.x - hf0);
    __hip_bfloat16 l1 = __float2bfloat16(v.y - hf1);
    ushort2 hp, lp;
    hp.x = *(unsigned short*)&h0; hp.y = *(unsigned short*)&h1;
    lp.x = *(unsigned short*)&l0; lp.y = *(unsigned short*)&l1;
    *(ushort2*)(XS + (size_t)row * 256 + lane * 2) = hp;
    *(ushort2*)(XS + (size_t)row * 256 + 128 + lane * 2) = lp;
    float s = fmaf(v.x, v.x, v.y * v.y);
    #pragma unroll
    for (int off = 32; off > 0; off >>= 1) s += __shfl_down(s, off);
    if (lane == 0) sq[row] = s;
}

// Strip-triangular pass, 64 KiB LDS (2 blocks/CU):
//   A_hi fragments in REGISTERS (loaded once per strip from XS),
//   A_lo resident LDS @0 (2x16K, staged once per strip),
//   B streamed through dbuf @32768 (2x16K), 4 panels/tile (hi0,hi1,lo0,lo1).
// Per B_hi panel: acc += A_hi(regs)xB + A_lo(LDS)xB; per B_lo panel: A_hi x B.
// Row-side top4/counts in registers across the strip; col-side per tile via
// scratch aliased in B1 (@49152) between barriers. Slot packing as before.
template <int PASS>
__global__ __launch_bounds__(256, 2)
void pass_kernel(const unsigned short* __restrict__ XS, const int* __restrict__ y,
                 const float* __restrict__ sq, const float* __restrict__ anchor,
                 float* __restrict__ top4p, int* __restrict__ cntp) {
    __shared__ __align__(16) char smem[65536];

    const int t = threadIdx.x;
    const int w = t >> 6, l = t & 63;
    const int wr = w >> 1, wc = w & 1;
    const int lg = l >> 4, lo16 = l & 15;

    // XCD swizzle (544 = 8*68) then strip decode
    const int bid = blockIdx.x;
    const int wg = (bid & 7) * (NBLKS / 8) + (bid >> 3);
    int it = 0, rem = wg;
    while (rem >= 16 - (it >> 2)) { rem -= 16 - (it >> 2); ++it; }
    const int s = (it >> 2) + rem;
    const int ibase = it * 128;
    const int jt_lo = (4 * s < it) ? it : 4 * s;
    const int jt_hi = 4 * s + 3;

    float sqi[16]; unsigned yiq[4]; float anc_i[16];
    #pragma unroll
    for (int mi = 0; mi < 4; ++mi) {
        unsigned pk = 0;
        #pragma unroll
        for (int r = 0; r < 4; ++r) {
            int row = ibase + wr * 64 + mi * 16 + lg * 4 + r;
            sqi[mi * 4 + r] = sq[row];
            if (PASS == 1) pk |= ((unsigned)y[row] & 255u) << (8 * r);
            else anc_i[mi * 4 + r] = anchor[row];
        }
        if (PASS == 1) yiq[mi] = pk;
    }

    // LDS read byte-offsets
    const int swz = (lo16 & 7) << 4;
    unsigned aoff[2], boff[2];
    #pragma unroll
    for (int kk = 0; kk < 2; ++kk) {
        const int cA = (kk * 64 + lg * 16) ^ swz;
        aoff[kk] = (unsigned)((wr * 64 + lo16) * 128 + cA);
        boff[kk] = (unsigned)(32768 + (wc * 64 + lo16) * 128 + cA);
    }
    // staging source (pre-swizzled column)
    const int srow = w * 32 + (l >> 3);
    const int scol = ((l & 7) ^ (l >> 3)) << 3;
    const unsigned short* gsrc = XS + (size_t)srow * 256 + scol;

    auto STAGE_B = [&](int jbase_rows, int p, int par) {
        char* Bb = smem + 32768 + par * 16384 + w * 4096;
        const unsigned short* gB = gsrc + (size_t)jbase_rows * 256 + p * 64;
        #pragma unroll
        for (int q = 0; q < 4; ++q)
            gload_lds16(gB + (size_t)q * 8 * 256, Bb + q * 1024);
    };

    // A_hi fragments -> registers (same bytes the swizzled LDS path would yield)
    short8 aHi[2][2][4];
    #pragma unroll
    for (int pan = 0; pan < 2; ++pan)
        #pragma unroll
        for (int kk = 0; kk < 2; ++kk)
            #pragma unroll
            for (int mi = 0; mi < 4; ++mi)
                aHi[pan][kk][mi] = *(const short8*)(
                    XS + (size_t)(ibase + wr * 64 + mi * 16 + lo16) * 256 + pan * 64 + kk * 32 + lg * 8);

    // stage A_lo (2 panels, resident) + first B panel
    #pragma unroll
    for (int pan = 0; pan < 2; ++pan)
        #pragma unroll
        for (int q = 0; q < 4; ++q)
            gload_lds16(gsrc + (size_t)ibase * 256 + 128 + pan * 64 + (size_t)q * 8 * 256,
                        smem + pan * 16384 + w * 4096 + q * 1024);
    STAGE_B(jt_lo * 128, 0, 0);

    float tp0[16], tp1[16], tp2[16], tp3[16];
    int cnt16[16];
    #pragma unroll
    for (int c = 0; c < 16; ++c) {
        if (PASS == 1) { tp0[c] = 1e30f; tp1[c] = 1e30f; tp2[c] = 1e30f; tp3[c] = 1e30f; }
        else cnt16[c] = 0;
    }

    __syncthreads();

    #pragma unroll 1
    for (int jt = jt_lo; jt <= jt_hi; ++jt) {
        const int jbase = jt * 128;
        const bool diag = (jt == it);

        float sqj[4]; int yj[4]; float anc_j[4];
        #pragma unroll
        for (int ni = 0; ni < 4; ++ni) {
            int col = jbase + wc * 64 + ni * 16 + lo16;
            sqj[ni] = sq[col];
            if (PASS == 1) yj[ni] = y[col];
            else anc_j[ni] = anchor[col];
        }

        f32x4 acc[4][4];
        f32x4 zz = {0.0f, 0.0f, 0.0f, 0.0f};
        #pragma unroll
        for (int mi = 0; mi < 4; ++mi)
            #pragma unroll
            for (int ni = 0; ni < 4; ++ni) acc[mi][ni] = zz;

        #pragma unroll
        for (int p = 0; p < 4; ++p) {
            const int par = p & 1;
            if (p < 3) STAGE_B(jbase, p + 1, par ^ 1);
            else if (jt < jt_hi) STAGE_B(jbase + 128, 0, par ^ 1);

            #pragma unroll
            for (int kk = 0; kk < 2; ++kk) {
                short8 bF[4];
                #pragma unroll
                for (int ni = 0; ni < 4; ++ni)
                    bF[ni] = *(const short8*)(smem + boff[kk] + par * 16384 + ni * 2048);
                #pragma unroll
                for (int mi = 0; mi < 4; ++mi)
                    #pragma unroll
                    for (int ni = 0; ni < 4; ++ni)
                        acc[mi][ni] = __builtin_amdgcn_mfma_f32_16x16x32_bf16(
                            aHi[p & 1][kk][mi], bF[ni], acc[mi][ni], 0, 0, 0);
                if (p < 2) {  // add A_lo x B_hi
                    short8 aL[4];
                    #pragma unroll
                    for (int mi = 0; mi < 4; ++mi)
                        aL[mi] = *(const short8*)(smem + (p & 1) * 16384 + aoff[kk] + mi * 2048);
                    #pragma unroll
                    for (int mi = 0; mi < 4; ++mi)
                        #pragma unroll
                        for (int ni = 0; ni < 4; ++ni)
                            acc[mi][ni] = __builtin_amdgcn_mfma_f32_16x16x32_bf16(
                                aL[mi], bF[ni], acc[mi][ni], 0, 0, 0);
                }
            }
            __syncthreads();
        }

        // tile epilogue (B1 @49152 is free until next STAGE_B targets it)
        if (PASS == 1) {
            float* scrC = (float*)(smem + 49152);   // [128][8]
            #pragma unroll
            for (int ni = 0; ni < 4; ++ni) {
                float c0 = 1e30f, c1 = 1e30f, c2 = 1e30f, c3 = 1e30f;
                #pragma unroll
                for (int mi = 0; mi < 4; ++mi)
                    #pragma unroll
                    for (int r = 0; r < 4; ++r) {
                        const int idx = mi * 4 + r;
                        float d2 = fmaf(-2.0f, acc[mi][ni][r], sqi[idx] + sqj[ni]);
                        d2 = fmaxf(d2, 0.0f);
                        bool same = (((yiq[mi] >> (8 * r)) & 255u) == (unsigned)yj[ni]);
                        float v = same ? d2 : 1e30f;
                        ins7(v, tp0[idx], tp1[idx], tp2[idx], tp3[idx]);
                        ins7(v, c0, c1, c2, c3);
                    }
                if (!diag) {
                    bmerge(16, c0, c1, c2, c3); bmerge(32, c0, c1, c2, c3);
                    if (lg == 0) {
                        int cl = wc * 64 + ni * 16 + lo16;
                        float4 st; st.x = c0; st.y = c1; st.z = c2; st.w = c3;
                        *(float4*)(scrC + cl * 8 + wr * 4) = st;
                    }
                }
            }
            if (!diag) {
                __syncthreads();
                if (t < 128) {
                    float4 qa = *(float4*)(scrC + t * 8);
                    float4 qb = *(float4*)(scrC + t * 8 + 4);
                    float b0 = qa.x, b1 = qa.y, b2 = qa.z, b3 = qa.w;
                    ins7(qb.x, b0, b1, b2, b3); ins7(qb.y, b0, b1, b2, b3);
                    ins7(qb.z, b0, b1, b2, b3); ins7(qb.w, b0, b1, b2, b3);
                    size_t base = ((size_t)(jbase + t) * NS + it) * 4;
                    top4p[base + 0] = b0; top4p[base + 1] = b1;
                    top4p[base + 2] = b2; top4p[base + 3] = b3;
                }
                __syncthreads();
            }
        } else {
            int* scrI = (int*)(smem + 49152);       // [128][2]
            #pragma unroll
            for (int ni = 0; ni < 4; ++ni) {
                int cc = 0;
                #pragma unroll
                for (int mi = 0; mi < 4; ++mi)
                    #pragma unroll
                    for (int r = 0; r < 4; ++r) {
                        const int idx = mi * 4 + r;
                        float d2 = fmaf(-2.0f, acc[mi][ni][r], sqi[idx] + sqj[ni]);
                        d2 = fmaxf(d2, 0.0f);
                        cnt16[idx] += (d2 <= anc_i[idx]) ? 1 : 0;
                        cc += (d2 <= anc_j[ni]) ? 1 : 0;
                    }
                if (!diag) {
                    cc += __shfl_xor(cc, 16); cc += __shfl_xor(cc, 32);
                    if (lg == 0) scrI[(wc * 64 + ni * 16 + lo16) * 2 + wr] = cc;
                }
            }
            if (!diag) {
                __syncthreads();
                if (t < 128)
                    cntp[(size_t)(jbase + t) * NS + it] = scrI[t * 2] + scrI[t * 2 + 1];
                __syncthreads();
            }
        }
    }

    // block-end row-side merge -> packed row slot it + (s - (it>>2))
    const int slot_row = it + (s - (it >> 2));
    if (PASS == 1) {
        float* scrR = (float*)smem;   // A_lo region dead now
        #pragma unroll
        for (int idx = 0; idx < 16; ++idx) {
            float v0 = tp0[idx], v1 = tp1[idx], v2 = tp2[idx], v3 = tp3[idx];
            bmerge(1, v0, v1, v2, v3); bmerge(2, v0, v1, v2, v3);
            bmerge(4, v0, v1, v2, v3); bmerge(8, v0, v1, v2, v3);
            if (lo16 == 0) {
                int rl = wr * 64 + (idx >> 2) * 16 + lg * 4 + (idx & 3);
                float4 st; st.x = v0; st.y = v1; st.z = v2; st.w = v3;
                *(float4*)(scrR + rl * 8 + wc * 4) = st;
            }
        }
        __syncthreads();
        if (t < 128) {
            float4 qa = *(float4*)(scrR + t * 8);
            float4 qb = *(float4*)(scrR + t * 8 + 4);
            float b0 = qa.x, b1 = qa.y, b2 = qa.z, b3 = qa.w;
            ins7(qb.x, b0, b1, b2, b3); ins7(qb.y, b0, b1, b2, b3);
            ins7(qb.z, b0, b1, b2, b3); ins7(qb.w, b0, b1, b2, b3);
            size_t base = ((size_t)(ibase + t) * NS + slot_row) * 4;
            top4p[base + 0] = b0; top4p[base + 1] = b1;
            top4p[base + 2] = b2; top4p[base + 3] = b3;
        }
    } else {
        int* scrI = (int*)smem;
        #pragma unroll
        for (int idx = 0; idx < 16; ++idx) {
            int c = cnt16[idx];
            c += __shfl_xor(c, 1); c += __shfl_xor(c, 2);
            c += __shfl_xor(c, 4); c += __shfl_xor(c, 8);
            if (lo16 == 0) {
                int rl = wr * 64 + (idx >> 2) * 16 + lg * 4 + (idx & 3);
                scrI[rl * 2 + wc] = c;
            }
        }
        __syncthreads();
        if (t < 128) cntp[(size_t)(ibase + t) * NS + slot_row] = scrI[t * 2] + scrI[t * 2 + 1];
    }
}

__global__ void anchor_kernel(const float* __restrict__ top4p, float* __restrict__ anchor) {
    int row = blockIdx.x * 256 + threadIdx.x;
    if (row >= NTOT) return;
    const int p = row >> 7;
    const int nvalid = p + 16 - (p >> 2);   // contiguous valid slots [0, nvalid)
    float b0 = 1e30f, b1 = 1e30f, b2 = 1e30f, b3 = 1e30f;
    const float4* q4 = (const float4*)(top4p + (size_t)row * NS * 4);
    for (int c = 0; c < nvalid; ++c) {
        float4 q = q4[c];
        ins7(q.x, b0, b1, b2, b3); ins7(q.y, b0, b1, b2, b3);
        ins7(q.z, b0, b1, b2, b3); ins7(q.w, b0, b1, b2, b3);
    }
    anchor[row] = b3;
}

// sum count partials -> digamma partial sums; class histogram (320 atomics total)
__global__ void reduce_kernel(const int* __restrict__ cntp, const int* __restrict__ y,
                              float* __restrict__ partials, int* __restrict__ cls) {
    __shared__ float red[256];
    __shared__ int hist[NCLS];
    int t = threadIdx.x;
    if (t < NCLS) hist[t] = 0;
    __syncthreads();
    int row = blockIdx.x * 256 + t;
    const int p = row >> 7;
    const int nvalid = p + 16 - (p >> 2);
    int s = 0;
    for (int c = 0; c < nvalid; ++c) s += cntp[(size_t)row * NS + c];
    atomicAdd(&hist[y[row]], 1);
    red[t] = digammaf_dev((float)(s - 1));
    __syncthreads();
    for (int h = 128; h > 0; h >>= 1) {
        if (t < h) red[t] += red[t + h];
        __syncthreads();
    }
    if (t == 0) partials[blockIdx.x] = red[0];
    if (t < NCLS) atomicAdd(&cls[t], hist[t]);
}

__global__ void finalize_kernel(const float* __restrict__ partials, const int* __restrict__ cls,
                                float* __restrict__ out) {
    if (threadIdx.x == 0) {
        float acc = 0.0f;
        for (int c = 0; c < NTOT / 256; ++c) acc += partials[c];
        float Nf = (float)NTOT;
        float avg_m = acc / Nf;
        float avgNx = 0.0f;
        for (int c = 0; c < NCLS; ++c) {
            float nx = (float)cls[c];
            if (nx > 0.0f) avgNx += (nx / Nf) * digammaf_dev(nx);
        }
        float mi = digammaf_dev(Nf) - avgNx + digammaf_dev(3.0f) - avg_m;
        out[0] = fmaxf(mi / logf(2.0f), 0.0f);
    }
}

extern "C" void kernel_launch(void* const* d_in, const int* in_sizes, int n_in,
                              void* d_out, int out_size, void* d_ws, size_t ws_size,
                              hipStream_t stream) {
    const float* X = (const float*)d_in[0];
    const int* y = (const int*)d_in[1];
    float* out = (float*)d_out;

    float* sq       = (float*)d_ws;                                   // 8192
    float* anchors  = sq + NTOT;                                      // 8192
    float* partials = anchors + NTOT;                                 // 32
    int*   cls      = (int*)(partials + 32);                          // 16
    unsigned short* XS = (unsigned short*)(cls + 16);                 // 8192*256 (4 MB)
    float* top4p    = (float*)(XS + (size_t)NTOT * 256);              // 8192*64*4 (8 MB)
    int*   cntp     = (int*)(top4p + (size_t)NTOT * NS * 4);          // 8192*64 (2 MB)

    zero_kernel<<<1, 64, 0, stream>>>(cls);
    prep_kernel<<<NTOT / 4, 256, 0, stream>>>(X, sq, XS);
    pass_kernel<1><<<NBLKS, 256, 0, stream>>>(XS, y, sq, anchors, top4p, cntp);
    anchor_kernel<<<NTOT / 256, 256, 0, stream>>>(top4p, anchors);
    pass_kernel<2><<<NBLKS, 256, 0, stream>>>(XS, y, sq, anchors, top4p, cntp);
    reduce_kernel<<<NTOT / 256, 256, 0, stream>>>(cntp, y, partials, cls);
    finalize_kernel<<<1, 64, 0, stream>>>(partials, cls, out);
}

// Round 10
// 136.649 us; speedup vs baseline: 1.6350x; 1.6350x over previous
//
#include <hip/hip_runtime.h>
#include <hip/hip_bf16.h>
#include <math.h>

#define NCLS 10
#define NTOT 8192
#define NTIL 64                    // 128-row panels per side
#define NJT 8                      // pass-2 j-tiles per block
#define NJG (NTOT / (128 * NJT))   // 8
#define NPMAX 9472                 // padded permuted rows upper bound
#define MAXSLOT 32                 // pass-1 partial slots per row
#define G1 2560                    // pass-1 grid upper bound (early-exit)

using short8 = __attribute__((ext_vector_type(8))) short;
using f32x4  = __attribute__((ext_vector_type(4))) float;

__device__ __forceinline__ float digammaf_dev(float x) {
    float r = 0.0f;
    while (x < 6.0f) { r -= 1.0f / x; x += 1.0f; }
    float inv = 1.0f / x;
    float inv2 = inv * inv;
    float s = logf(x) - 0.5f * inv
            - inv2 * (0.083333333333f - inv2 * (0.0083333333333f - inv2 * 0.0039682539683f));
    return r + s;
}

__device__ __forceinline__ void cmpswap(float& a, float& b) {
    float lo = fminf(a, b), hi = fmaxf(a, b);
    a = lo; b = hi;
}

__device__ __forceinline__ void ins7(float v, float& b0, float& b1, float& b2, float& b3) {
    float x0 = fminf(b0, v); float c0 = fmaxf(b0, v);
    float x1 = fminf(b1, c0); float c1 = fmaxf(b1, c0);
    float x2 = fminf(b2, c1); float c2 = fmaxf(b2, c1);
    float x3 = fminf(b3, c2);
    b0 = x0; b1 = x1; b2 = x2; b3 = x3;
}

__device__ __forceinline__ void bmerge(int mk, float& v0, float& v1, float& v2, float& v3) {
    float u0 = __shfl_xor(v0, mk), u1 = __shfl_xor(v1, mk);
    float u2 = __shfl_xor(v2, mk), u3 = __shfl_xor(v3, mk);
    float m0 = fminf(v0, u3), m1 = fminf(v1, u2);
    float m2 = fminf(v2, u1), m3 = fminf(v3, u0);
    cmpswap(m0, m2); cmpswap(m1, m3);
    cmpswap(m0, m1); cmpswap(m2, m3);
    v0 = m0; v1 = m1; v2 = m2; v3 = m3;
}

__device__ __forceinline__ void gload_lds16(const void* g, void* s) {
    __builtin_amdgcn_global_load_lds((const __attribute__((address_space(1))) void*)g,
                                     (__attribute__((address_space(3))) void*)s, 16, 0, 0);
}

__global__ void zero_kernel(int* cls) {
    if (threadIdx.x < 16) cls[threadIdx.x] = 0;
}

// per row: sq (fp32), XS[row][0..127]=hi(bf16), [128..255]=lo(bf16)
__global__ void prep_kernel(const float* __restrict__ X,
                            float* __restrict__ sq, unsigned short* __restrict__ XS) {
    int wave = threadIdx.x >> 6, lane = threadIdx.x & 63;
    int row = blockIdx.x * 4 + wave;
    float2 v = *(const float2*)(X + (size_t)row * 128 + lane * 2);
    __hip_bfloat16 h0 = __float2bfloat16(v.x);
    __hip_bfloat16 h1 = __float2bfloat16(v.y);
    float hf0 = __bfloat162float(h0), hf1 = __bfloat162float(h1);
    __hip_bfloat16 l0 = __float2bfloat16(v.x - hf0);
    __hip_bfloat16 l1 = __float2bfloat16(v.y - hf1);
    ushort2 hp, lp;
    hp.x = *(unsigned short*)&h0; hp.y = *(unsigned short*)&h1;
    lp.x = *(unsigned short*)&l0; lp.y = *(unsigned short*)&l1;
    *(ushort2*)(XS + (size_t)row * 256 + lane * 2) = hp;
    *(ushort2*)(XS + (size_t)row * 256 + 128 + lane * 2) = lp;
    float s = fmaf(v.x, v.x, v.y * v.y);
    #pragma unroll
    for (int off = 32; off > 0; off >>= 1) s += __shfl_down(s, off);
    if (lane == 0) sq[row] = s;
}

// per-block class counts (deterministic scatter prep) + global class totals
__global__ void count_kernel(const int* __restrict__ y, int* __restrict__ bcnt,
                             int* __restrict__ cls) {
    __shared__ int hist[NCLS];
    int t = threadIdx.x;
    if (t < NCLS) hist[t] = 0;
    __syncthreads();
    atomicAdd(&hist[y[blockIdx.x * 256 + t]], 1);
    __syncthreads();
    if (t < NCLS) {
        bcnt[blockIdx.x * NCLS + t] = hist[t];
        atomicAdd(&cls[t], hist[t]);
    }
}

// serial plan: per-class padded row base, tile count T, slots; per-(block,class)
// scatter offsets. plan[c]=rowBase, [10+c]=T, [20+c]=nslots, [30+c]=cumBlk, [40]=nBlocks
__global__ void plan_kernel(const int* __restrict__ bcnt, int* __restrict__ plan,
                            int* __restrict__ sOff) {
    if (threadIdx.x != 0) return;
    int rowBase = 0, cum = 0;
    for (int c = 0; c < NCLS; ++c) {
        int cnt = 0;
        for (int b = 0; b < 32; ++b) {
            sOff[b * NCLS + c] = rowBase + cnt;
            cnt += bcnt[b * NCLS + c];
        }
        int T = (cnt + 127) >> 7;
        int nsl = 0;
        if (T > 0) {
            int jstrip = (T + MAXSLOT - 1) / MAXSLOT;
            nsl = (T + jstrip - 1) / jstrip;
        }
        plan[c] = rowBase; plan[10 + c] = T; plan[20 + c] = nsl; plan[30 + c] = cum;
        rowBase += T << 7;
        cum += T * nsl;
    }
    plan[40] = cum;
}

__global__ void init_yP(int* __restrict__ yP) {
    yP[blockIdx.x * 256 + threadIdx.x] = -1;
}

// deterministic class-bucketed scatter: XS -> XSP (+ sqP, yP, idxP)
__global__ void scatter_kernel(const int* __restrict__ y, const float* __restrict__ sq,
                               const unsigned short* __restrict__ XS,
                               const int* __restrict__ sOff,
                               unsigned short* __restrict__ XSP, float* __restrict__ sqP,
                               int* __restrict__ yP, int* __restrict__ idxP) {
    __shared__ int yloc[256];
    __shared__ int dstloc[256];
    const int b = blockIdx.x, t = threadIdx.x;
    const int gid = b * 256 + t;
    const int yv = y[gid];
    yloc[t] = yv;
    __syncthreads();
    int rank = 0;
    for (int k = 0; k < 256; ++k) rank += (k < t && yloc[k] == yv) ? 1 : 0;
    const int dst = sOff[b * NCLS + yv] + rank;
    dstloc[t] = dst;
    sqP[dst] = sq[gid];
    yP[dst] = yv;
    idxP[dst] = gid;
    __syncthreads();
    const int w = t >> 6, l = t & 63;
    for (int r = w; r < 256; r += 4) {
        int d = dstloc[r];
        *(ushort4*)(XSP + (size_t)d * 256 + l * 4) =
            *(const ushort4*)(XS + (size_t)(b * 256 + r) * 256 + l * 4);
    }
}

// Pass 1 (class-bucketed): block -> (class c, row-tile itile, slot sIdx).
// Row-side top-4 only; orientation ALWAYS A=i (matches pass 2).
__global__ __launch_bounds__(256, 2)
void pass1_kernel(const unsigned short* __restrict__ XSP, const int* __restrict__ yP,
                  const float* __restrict__ sqP, const int* __restrict__ plan,
                  float* __restrict__ top4pP) {
    const int bid = blockIdx.x;
    if (bid >= plan[40]) return;
    __shared__ __align__(16) char smem[65536];

    const int t = threadIdx.x;
    const int w = t >> 6, l = t & 63;
    const int wr = w >> 1, wc = w & 1;
    const int lg = l >> 4, lo16 = l & 15;

    int cc = 0;
    #pragma unroll
    for (int q = 1; q < NCLS; ++q) if (bid >= plan[30 + q]) cc = q;
    const int rowBase = plan[cc], T = plan[10 + cc], nsl = plan[20 + cc];
    const int local = bid - plan[30 + cc];
    const int itile = local / nsl, sIdx = local % nsl;
    const int ibase = rowBase + itile * 128;

    float sqi[16]; int yi[16];
    #pragma unroll
    for (int mi = 0; mi < 4; ++mi)
        #pragma unroll
        for (int r = 0; r < 4; ++r) {
            int row = ibase + wr * 64 + mi * 16 + lg * 4 + r;
            sqi[mi * 4 + r] = sqP[row];
            yi[mi * 4 + r] = yP[row];
        }

    const int swz = (lo16 & 7) << 4;
    unsigned aoff[2], boff[2];
    #pragma unroll
    for (int kk = 0; kk < 2; ++kk) {
        const int cA = (kk * 64 + lg * 16) ^ swz;
        aoff[kk] = (unsigned)((wr * 64 + lo16) * 128 + cA);
        boff[kk] = (unsigned)(32768 + (wc * 64 + lo16) * 128 + cA);
    }
    const int srow = w * 32 + (l >> 3);
    const int scol = ((l & 7) ^ (l >> 3)) << 3;
    const unsigned short* gsrc = XSP + (size_t)srow * 256 + scol;

    auto STAGE = [&](int jbase_rows, int ks, int par) {
        if (ks < 2 || ks >= 4) {
            const int kA = (ks < 4) ? (ks & 1) * 64 : (ks - 2) * 64;
            char* Ab = smem + par * 16384 + w * 4096;
            const unsigned short* gA = gsrc + (size_t)ibase * 256 + kA;
            #pragma unroll
            for (int q = 0; q < 4; ++q)
                gload_lds16(gA + (size_t)q * 8 * 256, Ab + q * 1024);
        }
        const int kB = (ks < 4) ? ks * 64 : (ks - 4) * 64;
        char* Bb = smem + 32768 + par * 16384 + w * 4096;
        const unsigned short* gB = gsrc + (size_t)jbase_rows * 256 + kB;
        #pragma unroll
        for (int q = 0; q < 4; ++q)
            gload_lds16(gB + (size_t)q * 8 * 256, Bb + q * 1024);
    };

    float tp0[16], tp1[16], tp2[16], tp3[16];
    #pragma unroll
    for (int c = 0; c < 16; ++c) {
        tp0[c] = 1e30f; tp1[c] = 1e30f; tp2[c] = 1e30f; tp3[c] = 1e30f;
    }

    STAGE(rowBase + sIdx * 128, 0, 0);
    __syncthreads();

    #pragma unroll 1
    for (int jt = sIdx; jt < T; jt += nsl) {
        const int jbase = rowBase + jt * 128;
        float sqj[4]; int yj[4];
        #pragma unroll
        for (int ni = 0; ni < 4; ++ni) {
            int col = jbase + wc * 64 + ni * 16 + lo16;
            sqj[ni] = sqP[col];
            yj[ni] = yP[col];
        }
        f32x4 acc[4][4];
        f32x4 zz = {0.0f, 0.0f, 0.0f, 0.0f};
        #pragma unroll
        for (int mi = 0; mi < 4; ++mi)
            #pragma unroll
            for (int ni = 0; ni < 4; ++ni) acc[mi][ni] = zz;

        #pragma unroll
        for (int ks = 0; ks < 6; ++ks) {
            const int par = ks & 1;
            if (ks < 5) STAGE(jbase, ks + 1, par ^ 1);
            else if (jt + nsl < T) STAGE(rowBase + (jt + nsl) * 128, 0, par ^ 1);

            #pragma unroll
            for (int kk = 0; kk < 2; ++kk) {
                short8 aF[4], bF[4];
                #pragma unroll
                for (int mi = 0; mi < 4; ++mi)
                    aF[mi] = *(const short8*)(smem + aoff[kk] + par * 16384 + mi * 2048);
                #pragma unroll
                for (int ni = 0; ni < 4; ++ni)
                    bF[ni] = *(const short8*)(smem + boff[kk] + par * 16384 + ni * 2048);
                #pragma unroll
                for (int mi = 0; mi < 4; ++mi)
                    #pragma unroll
                    for (int ni = 0; ni < 4; ++ni)
                        acc[mi][ni] = __builtin_amdgcn_mfma_f32_16x16x32_bf16(
                            aF[mi], bF[ni], acc[mi][ni], 0, 0, 0);
            }

            if (ks == 5) {
                #pragma unroll
                for (int mi = 0; mi < 4; ++mi)
                    #pragma unroll
                    for (int r = 0; r < 4; ++r) {
                        const int idx = mi * 4 + r;
                        #pragma unroll
                        for (int ni = 0; ni < 4; ++ni) {
                            float d2 = fmaf(-2.0f, acc[mi][ni][r], sqi[idx] + sqj[ni]);
                            d2 = fmaxf(d2, 0.0f);
                            float v = (yi[idx] == yj[ni]) ? d2 : 1e30f;
                            ins7(v, tp0[idx], tp1[idx], tp2[idx], tp3[idx]);
                        }
                    }
            }
            __syncthreads();
        }
    }

    // block-end row-side merge -> slot sIdx
    float* scrR = (float*)smem;
    #pragma unroll
    for (int idx = 0; idx < 16; ++idx) {
        float v0 = tp0[idx], v1 = tp1[idx], v2 = tp2[idx], v3 = tp3[idx];
        bmerge(1, v0, v1, v2, v3); bmerge(2, v0, v1, v2, v3);
        bmerge(4, v0, v1, v2, v3); bmerge(8, v0, v1, v2, v3);
        if (lo16 == 0) {
            int rl = wr * 64 + (idx >> 2) * 16 + lg * 4 + (idx & 3);
            float4 st; st.x = v0; st.y = v1; st.z = v2; st.w = v3;
            *(float4*)(scrR + rl * 8 + wc * 4) = st;
        }
    }
    __syncthreads();
    if (t < 128) {
        float4 qa = *(float4*)(scrR + t * 8);
        float4 qb = *(float4*)(scrR + t * 8 + 4);
        float b0 = qa.x, b1 = qa.y, b2 = qa.z, b3 = qa.w;
        ins7(qb.x, b0, b1, b2, b3); ins7(qb.y, b0, b1, b2, b3);
        ins7(qb.z, b0, b1, b2, b3); ins7(qb.w, b0, b1, b2, b3);
        size_t base = ((size_t)(ibase + t) * MAXSLOT + sIdx) * 4;
        top4pP[base + 0] = b0; top4pP[base + 1] = b1;
        top4pP[base + 2] = b2; top4pP[base + 3] = b3;
    }
}

// merge pass-1 slots -> anchor (scattered back to original index)
__global__ void anchorP_kernel(const float* __restrict__ top4pP, const int* __restrict__ yP,
                               const int* __restrict__ idxP, const int* __restrict__ plan,
                               float* __restrict__ anchor) {
    int r = blockIdx.x * 256 + threadIdx.x;
    int yv = yP[r];
    if (yv < 0) return;
    int nsl = plan[20 + yv];
    float b0 = 1e30f, b1 = 1e30f, b2 = 1e30f, b3 = 1e30f;
    const float4* q4 = (const float4*)(top4pP + (size_t)r * MAXSLOT * 4);
    for (int s = 0; s < nsl; ++s) {
        float4 q = q4[s];
        ins7(q.x, b0, b1, b2, b3); ins7(q.y, b0, b1, b2, b3);
        ins7(q.z, b0, b1, b2, b3); ins7(q.w, b0, b1, b2, b3);
    }
    anchor[idxP[r]] = b3;
}

// Pass 2: FULL-SQUARE count (round-4 engine). Row-side counts only so every
// pair uses orientation A=i — bit-consistent with pass-1's anchors.
__global__ __launch_bounds__(256, 2)
void pass2_kernel(const unsigned short* __restrict__ XS, const float* __restrict__ sq,
                  const float* __restrict__ anchor, int* __restrict__ cntp) {
    __shared__ __align__(16) char smem[65536];

    const int t = threadIdx.x;
    const int w = t >> 6, l = t & 63;
    const int wr = w >> 1, wc = w & 1;
    const int lg = l >> 4, lo16 = l & 15;

    // XCD-aware bijective swizzle (512 % 8 == 0)
    const int bid = blockIdx.x;
    const int wg = (bid & 7) * ((NTIL * NJG) >> 3) + (bid >> 3);
    const int it = wg % NTIL, jg = wg / NTIL;
    const int ibase = it * 128;
    const int jg0 = jg * (128 * NJT);

    float sqi[16]; float anc[16];
    #pragma unroll
    for (int mi = 0; mi < 4; ++mi)
        #pragma unroll
        for (int r = 0; r < 4; ++r) {
            int row = ibase + wr * 64 + mi * 16 + lg * 4 + r;
            sqi[mi * 4 + r] = sq[row];
            anc[mi * 4 + r] = anchor[row];
        }

    const int swz = (lo16 & 7) << 4;
    unsigned aoff[2], boff[2];
    #pragma unroll
    for (int kk = 0; kk < 2; ++kk) {
        const int cA = (kk * 64 + lg * 16) ^ swz;
        aoff[kk] = (unsigned)((wr * 64 + lo16) * 128 + cA);
        boff[kk] = (unsigned)(32768 + (wc * 64 + lo16) * 128 + cA);
    }
    const int srow = w * 32 + (l >> 3);
    const int scol = ((l & 7) ^ (l >> 3)) << 3;
    const unsigned short* gsrc = XS + (size_t)srow * 256 + scol;

    auto STAGE = [&](int jbase_rows, int ks, int par) {
        if (ks < 2 || ks >= 4) {
            const int kA = (ks < 4) ? (ks & 1) * 64 : (ks - 2) * 64;
            char* Ab = smem + par * 16384 + w * 4096;
            const unsigned short* gA = gsrc + (size_t)ibase * 256 + kA;
            #pragma unroll
            for (int q = 0; q < 4; ++q)
                gload_lds16(gA + (size_t)q * 8 * 256, Ab + q * 1024);
        }
        const int kB = (ks < 4) ? ks * 64 : (ks - 4) * 64;
        char* Bb = smem + 32768 + par * 16384 + w * 4096;
        const unsigned short* gB = gsrc + (size_t)jbase_rows * 256 + kB;
        #pragma unroll
        for (int q = 0; q < 4; ++q)
            gload_lds16(gB + (size_t)q * 8 * 256, Bb + q * 1024);
    };

    int cnt16[16];
    #pragma unroll
    for (int c = 0; c < 16; ++c) cnt16[c] = 0;

    STAGE(jg0, 0, 0);
    __syncthreads();

    #pragma unroll 1
    for (int jt = 0; jt < NJT; ++jt) {
        const int jbase = jg0 + jt * 128;
        float sqj[4];
        #pragma unroll
        for (int ni = 0; ni < 4; ++ni)
            sqj[ni] = sq[jbase + wc * 64 + ni * 16 + lo16];

        f32x4 acc[4][4];
        f32x4 zz = {0.0f, 0.0f, 0.0f, 0.0f};
        #pragma unroll
        for (int mi = 0; mi < 4; ++mi)
            #pragma unroll
            for (int ni = 0; ni < 4; ++ni) acc[mi][ni] = zz;

        #pragma unroll
        for (int ks = 0; ks < 6; ++ks) {
            const int par = ks & 1;
            if (ks < 5) STAGE(jbase, ks + 1, par ^ 1);
            else if (jt < NJT - 1) STAGE(jbase + 128, 0, par ^ 1);

            #pragma unroll
            for (int kk = 0; kk < 2; ++kk) {
                short8 aF[4], bF[4];
                #pragma unroll
                for (int mi = 0; mi < 4; ++mi)
                    aF[mi] = *(const short8*)(smem + aoff[kk] + par * 16384 + mi * 2048);
                #pragma unroll
                for (int ni = 0; ni < 4; ++ni)
                    bF[ni] = *(const short8*)(smem + boff[kk] + par * 16384 + ni * 2048);
                #pragma unroll
                for (int mi = 0; mi < 4; ++mi)
                    #pragma unroll
                    for (int ni = 0; ni < 4; ++ni)
                        acc[mi][ni] = __builtin_amdgcn_mfma_f32_16x16x32_bf16(
                            aF[mi], bF[ni], acc[mi][ni], 0, 0, 0);
            }

            if (ks == 5) {
                #pragma unroll
                for (int mi = 0; mi < 4; ++mi)
                    #pragma unroll
                    for (int r = 0; r < 4; ++r) {
                        const int idx = mi * 4 + r;
                        int c = 0;
                        #pragma unroll
                        for (int ni = 0; ni < 4; ++ni) {
                            float d2 = fmaf(-2.0f, acc[mi][ni][r], sqi[idx] + sqj[ni]);
                            d2 = fmaxf(d2, 0.0f);
                            c += (d2 <= anc[idx]) ? 1 : 0;
                        }
                        cnt16[idx] += c;
                    }
            }
            __syncthreads();
        }
    }

    int* scri = (int*)smem;  // [128][2]
    #pragma unroll
    for (int idx = 0; idx < 16; ++idx) {
        int c = cnt16[idx];
        c += __shfl_xor(c, 1); c += __shfl_xor(c, 2);
        c += __shfl_xor(c, 4); c += __shfl_xor(c, 8);
        if (lo16 == 0) {
            int rl = wr * 64 + (idx >> 2) * 16 + lg * 4 + (idx & 3);
            scri[rl * 2 + wc] = c;
        }
    }
    __syncthreads();
    if (t < 128) cntp[(size_t)(ibase + t) * NJG + jg] = scri[t * 2] + scri[t * 2 + 1];
}

__global__ void reduce_kernel(const int* __restrict__ cntp, float* __restrict__ partials) {
    __shared__ float red[256];
    int t = threadIdx.x;
    int row = blockIdx.x * 256 + t;
    int s = 0;
    for (int c = 0; c < NJG; ++c) s += cntp[(size_t)row * NJG + c];
    red[t] = digammaf_dev((float)(s - 1));
    __syncthreads();
    for (int h = 128; h > 0; h >>= 1) {
        if (t < h) red[t] += red[t + h];
        __syncthreads();
    }
    if (t == 0) partials[blockIdx.x] = red[0];
}

__global__ void finalize_kernel(const float* __restrict__ partials, const int* __restrict__ cls,
                                float* __restrict__ out) {
    if (threadIdx.x == 0) {
        float acc = 0.0f;
        for (int c = 0; c < NTOT / 256; ++c) acc += partials[c];
        float Nf = (float)NTOT;
        float avg_m = acc / Nf;
        float avgNx = 0.0f;
        for (int c = 0; c < NCLS; ++c) {
            float nx = (float)cls[c];
            if (nx > 0.0f) avgNx += (nx / Nf) * digammaf_dev(nx);
        }
        float mi = digammaf_dev(Nf) - avgNx + digammaf_dev(3.0f) - avg_m;
        out[0] = fmaxf(mi / logf(2.0f), 0.0f);
    }
}

extern "C" void kernel_launch(void* const* d_in, const int* in_sizes, int n_in,
                              void* d_out, int out_size, void* d_ws, size_t ws_size,
                              hipStream_t stream) {
    const float* X = (const float*)d_in[0];
    const int* y = (const int*)d_in[1];
    float* out = (float*)d_out;

    float* sq       = (float*)d_ws;                                   // 8192
    float* anchors  = sq + NTOT;                                      // 8192
    float* partials = anchors + NTOT;                                 // 32
    int*   cls      = (int*)(partials + 32);                          // 16
    int*   bcnt     = cls + 16;                                       // 320
    int*   sOff     = bcnt + 320;                                     // 320
    int*   plan     = sOff + 320;                                     // 48
    int*   yP       = plan + 48;                                      // 9472
    int*   idxP     = yP + NPMAX;                                     // 9472
    float* sqP      = (float*)(idxP + NPMAX);                         // 9472
    unsigned short* XS  = (unsigned short*)(sqP + NPMAX);             // 8192*256 (4 MB)
    unsigned short* XSP = XS + (size_t)NTOT * 256;                    // 9472*256 (4.85 MB)
    float* top4pP   = (float*)(XSP + (size_t)NPMAX * 256);            // 9472*32*4 (4.85 MB)
    int*   cntp     = (int*)(top4pP + (size_t)NPMAX * MAXSLOT * 4);   // 8192*8

    zero_kernel<<<1, 64, 0, stream>>>(cls);
    prep_kernel<<<NTOT / 4, 256, 0, stream>>>(X, sq, XS);
    count_kernel<<<NTOT / 256, 256, 0, stream>>>(y, bcnt, cls);
    plan_kernel<<<1, 64, 0, stream>>>(bcnt, plan, sOff);
    init_yP<<<NPMAX / 256, 256, 0, stream>>>(yP);
    scatter_kernel<<<NTOT / 256, 256, 0, stream>>>(y, sq, XS, sOff, XSP, sqP, yP, idxP);
    pass1_kernel<<<G1, 256, 0, stream>>>(XSP, yP, sqP, plan, top4pP);
    anchorP_kernel<<<NPMAX / 256, 256, 0, stream>>>(top4pP, yP, idxP, plan, anchors);
    pass2_kernel<<<NTIL * NJG, 256, 0, stream>>>(XS, sq, anchors, cntp);
    reduce_kernel<<<NTOT / 256, 256, 0, stream>>>(cntp, partials);
    finalize_kernel<<<1, 64, 0, stream>>>(partials, cls, out);
}

// Round 11
// 133.904 us; speedup vs baseline: 1.6685x; 1.0205x over previous
//
#include <hip/hip_runtime.h>
#include <hip/hip_bf16.h>
#include <math.h>

#define NCLS 10
#define NTOT 8192
#define NTIL 64                    // 128-row panels per side
#define NJT 8                      // pass-2 j-tiles per block
#define NJG (NTOT / (128 * NJT))   // 8
#define NPMAX 9472                 // padded permuted rows upper bound
#define MAXSLOT 32                 // pass-1 partial slots per row
#define G1 2560                    // pass-1 grid upper bound (early-exit)

using short8 = __attribute__((ext_vector_type(8))) short;
using f32x4  = __attribute__((ext_vector_type(4))) float;

__device__ __forceinline__ float digammaf_dev(float x) {
    float r = 0.0f;
    while (x < 6.0f) { r -= 1.0f / x; x += 1.0f; }
    float inv = 1.0f / x;
    float inv2 = inv * inv;
    float s = logf(x) - 0.5f * inv
            - inv2 * (0.083333333333f - inv2 * (0.0083333333333f - inv2 * 0.0039682539683f));
    return r + s;
}

__device__ __forceinline__ void cmpswap(float& a, float& b) {
    float lo = fminf(a, b), hi = fmaxf(a, b);
    a = lo; b = hi;
}

__device__ __forceinline__ void ins7(float v, float& b0, float& b1, float& b2, float& b3) {
    float x0 = fminf(b0, v); float c0 = fmaxf(b0, v);
    float x1 = fminf(b1, c0); float c1 = fmaxf(b1, c0);
    float x2 = fminf(b2, c1); float c2 = fmaxf(b2, c1);
    float x3 = fminf(b3, c2);
    b0 = x0; b1 = x1; b2 = x2; b3 = x3;
}

__device__ __forceinline__ void bmerge(int mk, float& v0, float& v1, float& v2, float& v3) {
    float u0 = __shfl_xor(v0, mk), u1 = __shfl_xor(v1, mk);
    float u2 = __shfl_xor(v2, mk), u3 = __shfl_xor(v3, mk);
    float m0 = fminf(v0, u3), m1 = fminf(v1, u2);
    float m2 = fminf(v2, u1), m3 = fminf(v3, u0);
    cmpswap(m0, m2); cmpswap(m1, m3);
    cmpswap(m0, m1); cmpswap(m2, m3);
    v0 = m0; v1 = m1; v2 = m2; v3 = m3;
}

__device__ __forceinline__ void gload_lds16(const void* g, void* s) {
    __builtin_amdgcn_global_load_lds((const __attribute__((address_space(1))) void*)g,
                                     (__attribute__((address_space(3))) void*)s, 16, 0, 0);
}

// per row: sq (fp32), XS[row][0..127]=hi(bf16), [128..255]=lo(bf16)
__global__ void prep_kernel(const float* __restrict__ X,
                            float* __restrict__ sq, unsigned short* __restrict__ XS) {
    int wave = threadIdx.x >> 6, lane = threadIdx.x & 63;
    int row = blockIdx.x * 4 + wave;
    float2 v = *(const float2*)(X + (size_t)row * 128 + lane * 2);
    __hip_bfloat16 h0 = __float2bfloat16(v.x);
    __hip_bfloat16 h1 = __float2bfloat16(v.y);
    float hf0 = __bfloat162float(h0), hf1 = __bfloat162float(h1);
    __hip_bfloat16 l0 = __float2bfloat16(v.x - hf0);
    __hip_bfloat16 l1 = __float2bfloat16(v.y - hf1);
    ushort2 hp, lp;
    hp.x = *(unsigned short*)&h0; hp.y = *(unsigned short*)&h1;
    lp.x = *(unsigned short*)&l0; lp.y = *(unsigned short*)&l1;
    *(ushort2*)(XS + (size_t)row * 256 + lane * 2) = hp;
    *(ushort2*)(XS + (size_t)row * 256 + 128 + lane * 2) = lp;
    float s = fmaf(v.x, v.x, v.y * v.y);
    #pragma unroll
    for (int off = 32; off > 0; off >>= 1) s += __shfl_down(s, off);
    if (lane == 0) sq[row] = s;
}

// per-block class counts (deterministic scatter prep)
__global__ void count_kernel(const int* __restrict__ y, int* __restrict__ bcnt) {
    __shared__ int hist[NCLS];
    int t = threadIdx.x;
    if (t < NCLS) hist[t] = 0;
    __syncthreads();
    atomicAdd(&hist[y[blockIdx.x * 256 + t]], 1);
    __syncthreads();
    if (t < NCLS) bcnt[blockIdx.x * NCLS + t] = hist[t];
}

// parallel plan (1 wave): lane c scans 32 blocks for class c; lane 0 prefixes.
// plan[c]=rowBase, [10+c]=T, [20+c]=nsl (=ceil(T/2): 2 j-tiles/block),
// [30+c]=cumBlk, [40]=nBlocks. Also writes cls totals and sOff scatter bases.
__global__ void plan_kernel(const int* __restrict__ bcnt, int* __restrict__ plan,
                            int* __restrict__ sOff, int* __restrict__ cls) {
    __shared__ int sT[NCLS], sBase[NCLS];
    const int c = threadIdx.x;
    if (c < NCLS) {
        int run = 0;
        #pragma unroll 8
        for (int b = 0; b < 32; ++b) {
            sOff[b * NCLS + c] = run;            // local prefix; rowBase added below
            run += bcnt[b * NCLS + c];
        }
        cls[c] = run;
        sT[c] = (run + 127) >> 7;
    }
    __syncthreads();
    if (c == 0) {
        int rowBase = 0, cum = 0;
        for (int q = 0; q < NCLS; ++q) {
            int T = sT[q];
            int nsl = (T + 1) >> 1;
            sBase[q] = rowBase;
            plan[q] = rowBase;
            plan[10 + q] = T;
            plan[20 + q] = nsl;
            plan[30 + q] = cum;
            rowBase += T << 7;
            cum += T * nsl;
        }
        plan[40] = cum;
    }
    __syncthreads();
    if (c < NCLS) {
        int rb = sBase[c];
        #pragma unroll 8
        for (int b = 0; b < 32; ++b) sOff[b * NCLS + c] += rb;
    }
}

__global__ void init_yP(int* __restrict__ yP) {
    yP[blockIdx.x * 256 + threadIdx.x] = -1;
}

// deterministic class-bucketed scatter: XS -> XSP (+ sqP, yP, idxP)
__global__ void scatter_kernel(const int* __restrict__ y, const float* __restrict__ sq,
                               const unsigned short* __restrict__ XS,
                               const int* __restrict__ sOff,
                               unsigned short* __restrict__ XSP, float* __restrict__ sqP,
                               int* __restrict__ yP, int* __restrict__ idxP) {
    __shared__ int yloc[256];
    __shared__ int dstloc[256];
    const int b = blockIdx.x, t = threadIdx.x;
    const int gid = b * 256 + t;
    const int yv = y[gid];
    yloc[t] = yv;
    __syncthreads();
    int rank = 0;
    for (int k = 0; k < 256; ++k) rank += (k < t && yloc[k] == yv) ? 1 : 0;
    const int dst = sOff[b * NCLS + yv] + rank;
    dstloc[t] = dst;
    sqP[dst] = sq[gid];
    yP[dst] = yv;
    idxP[dst] = gid;
    __syncthreads();
    const int w = t >> 6, l = t & 63;
    for (int r = w; r < 256; r += 4) {
        int d = dstloc[r];
        *(ushort4*)(XSP + (size_t)d * 256 + l * 4) =
            *(const ushort4*)(XS + (size_t)(b * 256 + r) * 256 + l * 4);
    }
}

// Pass 1 (class-bucketed): block -> (class c, row-tile itile, slot sIdx).
// Covers j-tiles {sIdx, sIdx+nsl, ...} < T (2 tiles/block with nsl=ceil(T/2)).
// Row-side top-4 only; orientation ALWAYS A=i (matches pass 2).
__global__ __launch_bounds__(256, 2)
void pass1_kernel(const unsigned short* __restrict__ XSP, const int* __restrict__ yP,
                  const float* __restrict__ sqP, const int* __restrict__ plan,
                  float* __restrict__ top4pP) {
    const int bid = blockIdx.x;
    if (bid >= plan[40]) return;
    __shared__ __align__(16) char smem[65536];

    const int t = threadIdx.x;
    const int w = t >> 6, l = t & 63;
    const int wr = w >> 1, wc = w & 1;
    const int lg = l >> 4, lo16 = l & 15;

    int cc = 0;
    #pragma unroll
    for (int q = 1; q < NCLS; ++q) if (bid >= plan[30 + q]) cc = q;
    const int rowBase = plan[cc], T = plan[10 + cc], nsl = plan[20 + cc];
    const int local = bid - plan[30 + cc];
    const int itile = local / nsl, sIdx = local % nsl;
    const int ibase = rowBase + itile * 128;

    float sqi[16]; int yi[16];
    #pragma unroll
    for (int mi = 0; mi < 4; ++mi)
        #pragma unroll
        for (int r = 0; r < 4; ++r) {
            int row = ibase + wr * 64 + mi * 16 + lg * 4 + r;
            sqi[mi * 4 + r] = sqP[row];
            yi[mi * 4 + r] = yP[row];
        }

    const int swz = (lo16 & 7) << 4;
    unsigned aoff[2], boff[2];
    #pragma unroll
    for (int kk = 0; kk < 2; ++kk) {
        const int cA = (kk * 64 + lg * 16) ^ swz;
        aoff[kk] = (unsigned)((wr * 64 + lo16) * 128 + cA);
        boff[kk] = (unsigned)(32768 + (wc * 64 + lo16) * 128 + cA);
    }
    const int srow = w * 32 + (l >> 3);
    const int scol = ((l & 7) ^ (l >> 3)) << 3;
    const unsigned short* gsrc = XSP + (size_t)srow * 256 + scol;

    auto STAGE = [&](int jbase_rows, int ks, int par) {
        if (ks < 2 || ks >= 4) {
            const int kA = (ks < 4) ? (ks & 1) * 64 : (ks - 2) * 64;
            char* Ab = smem + par * 16384 + w * 4096;
            const unsigned short* gA = gsrc + (size_t)ibase * 256 + kA;
            #pragma unroll
            for (int q = 0; q < 4; ++q)
                gload_lds16(gA + (size_t)q * 8 * 256, Ab + q * 1024);
        }
        const int kB = (ks < 4) ? ks * 64 : (ks - 4) * 64;
        char* Bb = smem + 32768 + par * 16384 + w * 4096;
        const unsigned short* gB = gsrc + (size_t)jbase_rows * 256 + kB;
        #pragma unroll
        for (int q = 0; q < 4; ++q)
            gload_lds16(gB + (size_t)q * 8 * 256, Bb + q * 1024);
    };

    float tp0[16], tp1[16], tp2[16], tp3[16];
    #pragma unroll
    for (int c = 0; c < 16; ++c) {
        tp0[c] = 1e30f; tp1[c] = 1e30f; tp2[c] = 1e30f; tp3[c] = 1e30f;
    }

    STAGE(rowBase + sIdx * 128, 0, 0);
    __syncthreads();

    #pragma unroll 1
    for (int jt = sIdx; jt < T; jt += nsl) {
        const int jbase = rowBase + jt * 128;
        float sqj[4]; int yj[4];
        #pragma unroll
        for (int ni = 0; ni < 4; ++ni) {
            int col = jbase + wc * 64 + ni * 16 + lo16;
            sqj[ni] = sqP[col];
            yj[ni] = yP[col];
        }
        f32x4 acc[4][4];
        f32x4 zz = {0.0f, 0.0f, 0.0f, 0.0f};
        #pragma unroll
        for (int mi = 0; mi < 4; ++mi)
            #pragma unroll
            for (int ni = 0; ni < 4; ++ni) acc[mi][ni] = zz;

        #pragma unroll
        for (int ks = 0; ks < 6; ++ks) {
            const int par = ks & 1;
            if (ks < 5) STAGE(jbase, ks + 1, par ^ 1);
            else if (jt + nsl < T) STAGE(rowBase + (jt + nsl) * 128, 0, par ^ 1);

            #pragma unroll
            for (int kk = 0; kk < 2; ++kk) {
                short8 aF[4], bF[4];
                #pragma unroll
                for (int mi = 0; mi < 4; ++mi)
                    aF[mi] = *(const short8*)(smem + aoff[kk] + par * 16384 + mi * 2048);
                #pragma unroll
                for (int ni = 0; ni < 4; ++ni)
                    bF[ni] = *(const short8*)(smem + boff[kk] + par * 16384 + ni * 2048);
                #pragma unroll
                for (int mi = 0; mi < 4; ++mi)
                    #pragma unroll
                    for (int ni = 0; ni < 4; ++ni)
                        acc[mi][ni] = __builtin_amdgcn_mfma_f32_16x16x32_bf16(
                            aF[mi], bF[ni], acc[mi][ni], 0, 0, 0);
            }

            if (ks == 5) {
                #pragma unroll
                for (int mi = 0; mi < 4; ++mi)
                    #pragma unroll
                    for (int r = 0; r < 4; ++r) {
                        const int idx = mi * 4 + r;
                        #pragma unroll
                        for (int ni = 0; ni < 4; ++ni) {
                            float d2 = fmaf(-2.0f, acc[mi][ni][r], sqi[idx] + sqj[ni]);
                            d2 = fmaxf(d2, 0.0f);
                            float v = (yi[idx] == yj[ni]) ? d2 : 1e30f;
                            ins7(v, tp0[idx], tp1[idx], tp2[idx], tp3[idx]);
                        }
                    }
            }
            __syncthreads();
        }
    }

    // block-end row-side merge -> slot sIdx
    float* scrR = (float*)smem;
    #pragma unroll
    for (int idx = 0; idx < 16; ++idx) {
        float v0 = tp0[idx], v1 = tp1[idx], v2 = tp2[idx], v3 = tp3[idx];
        bmerge(1, v0, v1, v2, v3); bmerge(2, v0, v1, v2, v3);
        bmerge(4, v0, v1, v2, v3); bmerge(8, v0, v1, v2, v3);
        if (lo16 == 0) {
            int rl = wr * 64 + (idx >> 2) * 16 + lg * 4 + (idx & 3);
            float4 st; st.x = v0; st.y = v1; st.z = v2; st.w = v3;
            *(float4*)(scrR + rl * 8 + wc * 4) = st;
        }
    }
    __syncthreads();
    if (t < 128) {
        float4 qa = *(float4*)(scrR + t * 8);
        float4 qb = *(float4*)(scrR + t * 8 + 4);
        float b0 = qa.x, b1 = qa.y, b2 = qa.z, b3 = qa.w;
        ins7(qb.x, b0, b1, b2, b3); ins7(qb.y, b0, b1, b2, b3);
        ins7(qb.z, b0, b1, b2, b3); ins7(qb.w, b0, b1, b2, b3);
        size_t base = ((size_t)(ibase + t) * MAXSLOT + sIdx) * 4;
        top4pP[base + 0] = b0; top4pP[base + 1] = b1;
        top4pP[base + 2] = b2; top4pP[base + 3] = b3;
    }
}

// merge pass-1 slots -> anchor (scattered back to original index)
__global__ void anchorP_kernel(const float* __restrict__ top4pP, const int* __restrict__ yP,
                               const int* __restrict__ idxP, const int* __restrict__ plan,
                               float* __restrict__ anchor) {
    int r = blockIdx.x * 256 + threadIdx.x;
    int yv = yP[r];
    if (yv < 0) return;
    int nsl = plan[20 + yv];
    float b0 = 1e30f, b1 = 1e30f, b2 = 1e30f, b3 = 1e30f;
    const float4* q4 = (const float4*)(top4pP + (size_t)r * MAXSLOT * 4);
    for (int s = 0; s < nsl; ++s) {
        float4 q = q4[s];
        ins7(q.x, b0, b1, b2, b3); ins7(q.y, b0, b1, b2, b3);
        ins7(q.z, b0, b1, b2, b3); ins7(q.w, b0, b1, b2, b3);
    }
    anchor[idxP[r]] = b3;
}

// Pass 2: FULL-SQUARE count (round-4 engine). Row-side counts only so every
// pair uses orientation A=i — bit-consistent with pass-1's anchors.
__global__ __launch_bounds__(256, 2)
void pass2_kernel(const unsigned short* __restrict__ XS, const float* __restrict__ sq,
                  const float* __restrict__ anchor, int* __restrict__ cntp) {
    __shared__ __align__(16) char smem[65536];

    const int t = threadIdx.x;
    const int w = t >> 6, l = t & 63;
    const int wr = w >> 1, wc = w & 1;
    const int lg = l >> 4, lo16 = l & 15;

    // XCD-aware bijective swizzle (512 % 8 == 0)
    const int bid = blockIdx.x;
    const int wg = (bid & 7) * ((NTIL * NJG) >> 3) + (bid >> 3);
    const int it = wg % NTIL, jg = wg / NTIL;
    const int ibase = it * 128;
    const int jg0 = jg * (128 * NJT);

    float sqi[16]; float anc[16];
    #pragma unroll
    for (int mi = 0; mi < 4; ++mi)
        #pragma unroll
        for (int r = 0; r < 4; ++r) {
            int row = ibase + wr * 64 + mi * 16 + lg * 4 + r;
            sqi[mi * 4 + r] = sq[row];
            anc[mi * 4 + r] = anchor[row];
        }

    const int swz = (lo16 & 7) << 4;
    unsigned aoff[2], boff[2];
    #pragma unroll
    for (int kk = 0; kk < 2; ++kk) {
        const int cA = (kk * 64 + lg * 16) ^ swz;
        aoff[kk] = (unsigned)((wr * 64 + lo16) * 128 + cA);
        boff[kk] = (unsigned)(32768 + (wc * 64 + lo16) * 128 + cA);
    }
    const int srow = w * 32 + (l >> 3);
    const int scol = ((l & 7) ^ (l >> 3)) << 3;
    const unsigned short* gsrc = XS + (size_t)srow * 256 + scol;

    auto STAGE = [&](int jbase_rows, int ks, int par) {
        if (ks < 2 || ks >= 4) {
            const int kA = (ks < 4) ? (ks & 1) * 64 : (ks - 2) * 64;
            char* Ab = smem + par * 16384 + w * 4096;
            const unsigned short* gA = gsrc + (size_t)ibase * 256 + kA;
            #pragma unroll
            for (int q = 0; q < 4; ++q)
                gload_lds16(gA + (size_t)q * 8 * 256, Ab + q * 1024);
        }
        const int kB = (ks < 4) ? ks * 64 : (ks - 4) * 64;
        char* Bb = smem + 32768 + par * 16384 + w * 4096;
        const unsigned short* gB = gsrc + (size_t)jbase_rows * 256 + kB;
        #pragma unroll
        for (int q = 0; q < 4; ++q)
            gload_lds16(gB + (size_t)q * 8 * 256, Bb + q * 1024);
    };

    int cnt16[16];
    #pragma unroll
    for (int c = 0; c < 16; ++c) cnt16[c] = 0;

    STAGE(jg0, 0, 0);
    __syncthreads();

    #pragma unroll 1
    for (int jt = 0; jt < NJT; ++jt) {
        const int jbase = jg0 + jt * 128;
        float sqj[4];
        #pragma unroll
        for (int ni = 0; ni < 4; ++ni)
            sqj[ni] = sq[jbase + wc * 64 + ni * 16 + lo16];

        f32x4 acc[4][4];
        f32x4 zz = {0.0f, 0.0f, 0.0f, 0.0f};
        #pragma unroll
        for (int mi = 0; mi < 4; ++mi)
            #pragma unroll
            for (int ni = 0; ni < 4; ++ni) acc[mi][ni] = zz;

        #pragma unroll
        for (int ks = 0; ks < 6; ++ks) {
            const int par = ks & 1;
            if (ks < 5) STAGE(jbase, ks + 1, par ^ 1);
            else if (jt < NJT - 1) STAGE(jbase + 128, 0, par ^ 1);

            #pragma unroll
            for (int kk = 0; kk < 2; ++kk) {
                short8 aF[4], bF[4];
                #pragma unroll
                for (int mi = 0; mi < 4; ++mi)
                    aF[mi] = *(const short8*)(smem + aoff[kk] + par * 16384 + mi * 2048);
                #pragma unroll
                for (int ni = 0; ni < 4; ++ni)
                    bF[ni] = *(const short8*)(smem + boff[kk] + par * 16384 + ni * 2048);
                #pragma unroll
                for (int mi = 0; mi < 4; ++mi)
                    #pragma unroll
                    for (int ni = 0; ni < 4; ++ni)
                        acc[mi][ni] = __builtin_amdgcn_mfma_f32_16x16x32_bf16(
                            aF[mi], bF[ni], acc[mi][ni], 0, 0, 0);
            }

            if (ks == 5) {
                #pragma unroll
                for (int mi = 0; mi < 4; ++mi)
                    #pragma unroll
                    for (int r = 0; r < 4; ++r) {
                        const int idx = mi * 4 + r;
                        int c = 0;
                        #pragma unroll
                        for (int ni = 0; ni < 4; ++ni) {
                            float d2 = fmaf(-2.0f, acc[mi][ni][r], sqi[idx] + sqj[ni]);
                            d2 = fmaxf(d2, 0.0f);
                            c += (d2 <= anc[idx]) ? 1 : 0;
                        }
                        cnt16[idx] += c;
                    }
            }
            __syncthreads();
        }
    }

    int* scri = (int*)smem;  // [128][2]
    #pragma unroll
    for (int idx = 0; idx < 16; ++idx) {
        int c = cnt16[idx];
        c += __shfl_xor(c, 1); c += __shfl_xor(c, 2);
        c += __shfl_xor(c, 4); c += __shfl_xor(c, 8);
        if (lo16 == 0) {
            int rl = wr * 64 + (idx >> 2) * 16 + lg * 4 + (idx & 3);
            scri[rl * 2 + wc] = c;
        }
    }
    __syncthreads();
    if (t < 128) cntp[(size_t)(ibase + t) * NJG + jg] = scri[t * 2] + scri[t * 2 + 1];
}

__global__ void reduce_kernel(const int* __restrict__ cntp, float* __restrict__ partials) {
    __shared__ float red[256];
    int t = threadIdx.x;
    int row = blockIdx.x * 256 + t;
    int s = 0;
    for (int c = 0; c < NJG; ++c) s += cntp[(size_t)row * NJG + c];
    red[t] = digammaf_dev((float)(s - 1));
    __syncthreads();
    for (int h = 128; h > 0; h >>= 1) {
        if (t < h) red[t] += red[t + h];
        __syncthreads();
    }
    if (t == 0) partials[blockIdx.x] = red[0];
}

__global__ void finalize_kernel(const float* __restrict__ partials, const int* __restrict__ cls,
                                float* __restrict__ out) {
    if (threadIdx.x == 0) {
        float acc = 0.0f;
        for (int c = 0; c < NTOT / 256; ++c) acc += partials[c];
        float Nf = (float)NTOT;
        float avg_m = acc / Nf;
        float avgNx = 0.0f;
        for (int c = 0; c < NCLS; ++c) {
            float nx = (float)cls[c];
            if (nx > 0.0f) avgNx += (nx / Nf) * digammaf_dev(nx);
        }
        float mi = digammaf_dev(Nf) - avgNx + digammaf_dev(3.0f) - avg_m;
        out[0] = fmaxf(mi / logf(2.0f), 0.0f);
    }
}

extern "C" void kernel_launch(void* const* d_in, const int* in_sizes, int n_in,
                              void* d_out, int out_size, void* d_ws, size_t ws_size,
                              hipStream_t stream) {
    const float* X = (const float*)d_in[0];
    const int* y = (const int*)d_in[1];
    float* out = (float*)d_out;

    float* sq       = (float*)d_ws;                                   // 8192
    float* anchors  = sq + NTOT;                                      // 8192
    float* partials = anchors + NTOT;                                 // 32
    int*   cls      = (int*)(partials + 32);                          // 16
    int*   bcnt     = cls + 16;                                       // 320
    int*   sOff     = bcnt + 320;                                     // 320
    int*   plan     = sOff + 320;                                     // 48
    int*   yP       = plan + 48;                                      // 9472
    int*   idxP     = yP + NPMAX;                                     // 9472
    float* sqP      = (float*)(idxP + NPMAX);                         // 9472
    unsigned short* XS  = (unsigned short*)(sqP + NPMAX);             // 8192*256 (4 MB)
    unsigned short* XSP = XS + (size_t)NTOT * 256;                    // 9472*256 (4.85 MB)
    float* top4pP   = (float*)(XSP + (size_t)NPMAX * 256);            // 9472*32*4 (4.85 MB)
    int*   cntp     = (int*)(top4pP + (size_t)NPMAX * MAXSLOT * 4);   // 8192*8

    prep_kernel<<<NTOT / 4, 256, 0, stream>>>(X, sq, XS);
    count_kernel<<<NTOT / 256, 256, 0, stream>>>(y, bcnt);
    plan_kernel<<<1, 64, 0, stream>>>(bcnt, plan, sOff, cls);
    init_yP<<<NPMAX / 256, 256, 0, stream>>>(yP);
    scatter_kernel<<<NTOT / 256, 256, 0, stream>>>(y, sq, XS, sOff, XSP, sqP, yP, idxP);
    pass1_kernel<<<G1, 256, 0, stream>>>(XSP, yP, sqP, plan, top4pP);
    anchorP_kernel<<<NPMAX / 256, 256, 0, stream>>>(top4pP, yP, idxP, plan, anchors);
    pass2_kernel<<<NTIL * NJG, 256, 0, stream>>>(XS, sq, anchors, cntp);
    reduce_kernel<<<NTOT / 256, 256, 0, stream>>>(cntp, partials);
    finalize_kernel<<<1, 64, 0, stream>>>(partials, cls, out);
}

// Round 12
// 127.167 us; speedup vs baseline: 1.7569x; 1.0530x over previous
//
#include <hip/hip_runtime.h>
#include <hip/hip_bf16.h>
#include <math.h>

#define NCLS 10
#define NTOT 8192
#define NTIL 64                    // 128-row panels per side
#define NJT 8                      // pass-2 j-tiles per block
#define NJG (NTOT / (128 * NJT))   // 8
#define NPMAX 9472                 // padded permuted rows upper bound
#define MAXSLOT 32                 // pass-1 partial slots per row
#define G1 3072                    // pass-1 grid upper bound (early-exit)

using short8 = __attribute__((ext_vector_type(8))) short;
using f32x4  = __attribute__((ext_vector_type(4))) float;

__device__ __forceinline__ float digammaf_dev(float x) {
    float r = 0.0f;
    while (x < 6.0f) { r -= 1.0f / x; x += 1.0f; }
    float inv = 1.0f / x;
    float inv2 = inv * inv;
    float s = logf(x) - 0.5f * inv
            - inv2 * (0.083333333333f - inv2 * (0.0083333333333f - inv2 * 0.0039682539683f));
    return r + s;
}

__device__ __forceinline__ void cmpswap(float& a, float& b) {
    float lo = fminf(a, b), hi = fmaxf(a, b);
    a = lo; b = hi;
}

__device__ __forceinline__ void ins7(float v, float& b0, float& b1, float& b2, float& b3) {
    float x0 = fminf(b0, v); float c0 = fmaxf(b0, v);
    float x1 = fminf(b1, c0); float c1 = fmaxf(b1, c0);
    float x2 = fminf(b2, c1); float c2 = fmaxf(b2, c1);
    float x3 = fminf(b3, c2);
    b0 = x0; b1 = x1; b2 = x2; b3 = x3;
}

__device__ __forceinline__ void bmerge(int mk, float& v0, float& v1, float& v2, float& v3) {
    float u0 = __shfl_xor(v0, mk), u1 = __shfl_xor(v1, mk);
    float u2 = __shfl_xor(v2, mk), u3 = __shfl_xor(v3, mk);
    float m0 = fminf(v0, u3), m1 = fminf(v1, u2);
    float m2 = fminf(v2, u1), m3 = fminf(v3, u0);
    cmpswap(m0, m2); cmpswap(m1, m3);
    cmpswap(m0, m1); cmpswap(m2, m3);
    v0 = m0; v1 = m1; v2 = m2; v3 = m3;
}

__device__ __forceinline__ void gload_lds16(const void* g, void* s) {
    __builtin_amdgcn_global_load_lds((const __attribute__((address_space(1))) void*)g,
                                     (__attribute__((address_space(3))) void*)s, 16, 0, 0);
}

// per row: sq (fp32), XS[row][0..127]=hi(bf16), [128..255]=lo(bf16)
__global__ void prep_kernel(const float* __restrict__ X,
                            float* __restrict__ sq, unsigned short* __restrict__ XS) {
    int wave = threadIdx.x >> 6, lane = threadIdx.x & 63;
    int row = blockIdx.x * 4 + wave;
    float2 v = *(const float2*)(X + (size_t)row * 128 + lane * 2);
    __hip_bfloat16 h0 = __float2bfloat16(v.x);
    __hip_bfloat16 h1 = __float2bfloat16(v.y);
    float hf0 = __bfloat162float(h0), hf1 = __bfloat162float(h1);
    __hip_bfloat16 l0 = __float2bfloat16(v.x - hf0);
    __hip_bfloat16 l1 = __float2bfloat16(v.y - hf1);
    ushort2 hp, lp;
    hp.x = *(unsigned short*)&h0; hp.y = *(unsigned short*)&h1;
    lp.x = *(unsigned short*)&l0; lp.y = *(unsigned short*)&l1;
    *(ushort2*)(XS + (size_t)row * 256 + lane * 2) = hp;
    *(ushort2*)(XS + (size_t)row * 256 + 128 + lane * 2) = lp;
    float s = fmaf(v.x, v.x, v.y * v.y);
    #pragma unroll
    for (int off = 32; off > 0; off >>= 1) s += __shfl_down(s, off);
    if (lane == 0) sq[row] = s;
}

// per-block class counts (deterministic scatter prep)
__global__ void count_kernel(const int* __restrict__ y, int* __restrict__ bcnt) {
    __shared__ int hist[NCLS];
    int t = threadIdx.x;
    if (t < NCLS) hist[t] = 0;
    __syncthreads();
    atomicAdd(&hist[y[blockIdx.x * 256 + t]], 1);
    __syncthreads();
    if (t < NCLS) bcnt[blockIdx.x * NCLS + t] = hist[t];
}

// plan (1 block, 256 thr): also inits yP padding and writes cls totals.
// plan[c]=rowBase, [10+c]=T, [20+c]=T (slot count), [30+c]=cumBlk (2*T*T per
// class: 64-row i-halves x T j-tiles), [40]=nBlocks.
__global__ void plan_kernel(const int* __restrict__ bcnt, int* __restrict__ plan,
                            int* __restrict__ sOff, int* __restrict__ cls,
                            int* __restrict__ yP) {
    __shared__ int sT[NCLS], sBase[NCLS];
    const int c = threadIdx.x;
    for (int i = c; i < NPMAX; i += 256) yP[i] = -1;
    if (c < NCLS) {
        int run = 0;
        #pragma unroll 8
        for (int b = 0; b < 32; ++b) {
            sOff[b * NCLS + c] = run;            // local prefix; rowBase added below
            run += bcnt[b * NCLS + c];
        }
        cls[c] = run;
        sT[c] = (run + 127) >> 7;
    }
    __syncthreads();
    if (c == 0) {
        int rowBase = 0, cum = 0;
        for (int q = 0; q < NCLS; ++q) {
            int T = sT[q];
            sBase[q] = rowBase;
            plan[q] = rowBase;
            plan[10 + q] = T;
            plan[20 + q] = T;
            plan[30 + q] = cum;
            rowBase += T << 7;
            cum += 2 * T * T;
        }
        plan[40] = cum;
    }
    __syncthreads();
    if (c < NCLS) {
        int rb = sBase[c];
        #pragma unroll 8
        for (int b = 0; b < 32; ++b) sOff[b * NCLS + c] += rb;
    }
}

// deterministic class-bucketed scatter: XS -> XSP (+ sqP, yP, idxP)
__global__ void scatter_kernel(const int* __restrict__ y, const float* __restrict__ sq,
                               const unsigned short* __restrict__ XS,
                               const int* __restrict__ sOff,
                               unsigned short* __restrict__ XSP, float* __restrict__ sqP,
                               int* __restrict__ yP, int* __restrict__ idxP) {
    __shared__ int yloc[256];
    __shared__ int dstloc[256];
    const int b = blockIdx.x, t = threadIdx.x;
    const int gid = b * 256 + t;
    const int yv = y[gid];
    yloc[t] = yv;
    __syncthreads();
    int rank = 0;
    for (int k = 0; k < 256; ++k) rank += (k < t && yloc[k] == yv) ? 1 : 0;
    const int dst = sOff[b * NCLS + yv] + rank;
    dstloc[t] = dst;
    sqP[dst] = sq[gid];
    yP[dst] = yv;
    idxP[dst] = gid;
    __syncthreads();
    const int w = t >> 6, l = t & 63;
    for (int r = w; r < 256; r += 4) {
        int d = dstloc[r];
        *(ushort4*)(XSP + (size_t)d * 256 + l * 4) =
            *(const ushort4*)(XS + (size_t)(b * 256 + r) * 256 + l * 4);
    }
}

// Pass 1 (class-bucketed, 64x128 tiles): block -> (class c, i-half, j-tile).
// One tile per block, 980-ish blocks, 48KB LDS -> 3 blocks/CU co-resident.
// d2 chain bit-identical to pass 2 (same panel order + fragment mapping).
__global__ __launch_bounds__(256, 2)
void pass1_kernel(const unsigned short* __restrict__ XSP, const int* __restrict__ yP,
                  const float* __restrict__ sqP, const int* __restrict__ plan,
                  float* __restrict__ top4pP) {
    const int bid = blockIdx.x;
    if (bid >= plan[40]) return;
    __shared__ __align__(16) char smem[49152];   // A dbuf 2x8K @0; B dbuf 2x16K @16384

    const int t = threadIdx.x;
    const int w = t >> 6, l = t & 63;
    const int wr = w >> 1, wc = w & 1;
    const int lg = l >> 4, lo16 = l & 15;

    int cc = 0;
    #pragma unroll
    for (int q = 1; q < NCLS; ++q) if (bid >= plan[30 + q]) cc = q;
    const int rowBase = plan[cc], T = plan[10 + cc];
    const int local = bid - plan[30 + cc];
    const int jt = local % T;
    const int itile2 = local / T;
    const int ibase = rowBase + (itile2 >> 1) * 128 + (itile2 & 1) * 64;
    const int jbase = rowBase + jt * 128;

    float sqi[8]; int yi[8];
    #pragma unroll
    for (int mi = 0; mi < 2; ++mi)
        #pragma unroll
        for (int r = 0; r < 4; ++r) {
            int row = ibase + wr * 32 + mi * 16 + lg * 4 + r;
            sqi[mi * 4 + r] = sqP[row];
            yi[mi * 4 + r] = yP[row];
        }
    float sqj[4]; int yj[4];
    #pragma unroll
    for (int ni = 0; ni < 4; ++ni) {
        int col = jbase + wc * 64 + ni * 16 + lo16;
        sqj[ni] = sqP[col];
        yj[ni] = yP[col];
    }

    const int swz = (lo16 & 7) << 4;
    unsigned aoff[2], boff[2];
    #pragma unroll
    for (int kk = 0; kk < 2; ++kk) {
        const int cA = (kk * 64 + lg * 16) ^ swz;
        aoff[kk] = (unsigned)((wr * 32 + lo16) * 128 + cA);
        boff[kk] = (unsigned)(16384 + (wc * 64 + lo16) * 128 + cA);
    }
    const int scol = ((l & 7) ^ (l >> 3)) << 3;
    const unsigned short* gsrcA = XSP + (size_t)(w * 16 + (l >> 3)) * 256 + scol;
    const unsigned short* gsrcB = XSP + (size_t)(w * 32 + (l >> 3)) * 256 + scol;

    auto STAGE = [&](int ks, int par) {
        if (ks < 2 || ks >= 4) {
            const int kA = (ks < 4) ? (ks & 1) * 64 : (ks - 2) * 64;
            char* Ab = smem + par * 8192 + w * 2048;
            const unsigned short* gA = gsrcA + (size_t)ibase * 256 + kA;
            #pragma unroll
            for (int q = 0; q < 2; ++q)
                gload_lds16(gA + (size_t)q * 8 * 256, Ab + q * 1024);
        }
        const int kB = (ks < 4) ? ks * 64 : (ks - 4) * 64;
        char* Bb = smem + 16384 + par * 16384 + w * 4096;
        const unsigned short* gB = gsrcB + (size_t)jbase * 256 + kB;
        #pragma unroll
        for (int q = 0; q < 4; ++q)
            gload_lds16(gB + (size_t)q * 8 * 256, Bb + q * 1024);
    };

    float tp0[8], tp1[8], tp2[8], tp3[8];
    #pragma unroll
    for (int c = 0; c < 8; ++c) {
        tp0[c] = 1e30f; tp1[c] = 1e30f; tp2[c] = 1e30f; tp3[c] = 1e30f;
    }

    f32x4 acc[2][4];
    f32x4 zz = {0.0f, 0.0f, 0.0f, 0.0f};
    #pragma unroll
    for (int mi = 0; mi < 2; ++mi)
        #pragma unroll
        for (int ni = 0; ni < 4; ++ni) acc[mi][ni] = zz;

    STAGE(0, 0);
    __syncthreads();

    #pragma unroll
    for (int ks = 0; ks < 6; ++ks) {
        const int par = ks & 1;
        if (ks < 5) STAGE(ks + 1, par ^ 1);
        #pragma unroll
        for (int kk = 0; kk < 2; ++kk) {
            short8 aF[2], bF[4];
            #pragma unroll
            for (int mi = 0; mi < 2; ++mi)
                aF[mi] = *(const short8*)(smem + aoff[kk] + par * 8192 + mi * 2048);
            #pragma unroll
            for (int ni = 0; ni < 4; ++ni)
                bF[ni] = *(const short8*)(smem + boff[kk] + par * 16384 + ni * 2048);
            #pragma unroll
            for (int mi = 0; mi < 2; ++mi)
                #pragma unroll
                for (int ni = 0; ni < 4; ++ni)
                    acc[mi][ni] = __builtin_amdgcn_mfma_f32_16x16x32_bf16(
                        aF[mi], bF[ni], acc[mi][ni], 0, 0, 0);
        }
        if (ks == 5) {
            #pragma unroll
            for (int mi = 0; mi < 2; ++mi)
                #pragma unroll
                for (int r = 0; r < 4; ++r) {
                    const int idx = mi * 4 + r;
                    #pragma unroll
                    for (int ni = 0; ni < 4; ++ni) {
                        float d2 = fmaf(-2.0f, acc[mi][ni][r], sqi[idx] + sqj[ni]);
                        d2 = fmaxf(d2, 0.0f);
                        float v = (yi[idx] == yj[ni]) ? d2 : 1e30f;
                        ins7(v, tp0[idx], tp1[idx], tp2[idx], tp3[idx]);
                    }
                }
        }
        __syncthreads();
    }

    // cross-lane + cross-wave merge -> slot jt
    float* scrR = (float*)smem;   // [64 rows][2 wc][4]
    #pragma unroll
    for (int idx = 0; idx < 8; ++idx) {
        float v0 = tp0[idx], v1 = tp1[idx], v2 = tp2[idx], v3 = tp3[idx];
        bmerge(1, v0, v1, v2, v3); bmerge(2, v0, v1, v2, v3);
        bmerge(4, v0, v1, v2, v3); bmerge(8, v0, v1, v2, v3);
        if (lo16 == 0) {
            int rl = wr * 32 + (idx >> 2) * 16 + lg * 4 + (idx & 3);
            float4 st; st.x = v0; st.y = v1; st.z = v2; st.w = v3;
            *(float4*)(scrR + rl * 8 + wc * 4) = st;
        }
    }
    __syncthreads();
    if (t < 64) {
        float4 qa = *(float4*)(scrR + t * 8);
        float4 qb = *(float4*)(scrR + t * 8 + 4);
        float b0 = qa.x, b1 = qa.y, b2 = qa.z, b3 = qa.w;
        ins7(qb.x, b0, b1, b2, b3); ins7(qb.y, b0, b1, b2, b3);
        ins7(qb.z, b0, b1, b2, b3); ins7(qb.w, b0, b1, b2, b3);
        size_t base = ((size_t)(ibase + t) * MAXSLOT + jt) * 4;
        top4pP[base + 0] = b0; top4pP[base + 1] = b1;
        top4pP[base + 2] = b2; top4pP[base + 3] = b3;
    }
}

// merge pass-1 slots -> anchor (scattered back to original index)
__global__ void anchorP_kernel(const float* __restrict__ top4pP, const int* __restrict__ yP,
                               const int* __restrict__ idxP, const int* __restrict__ plan,
                               float* __restrict__ anchor) {
    int r = blockIdx.x * 256 + threadIdx.x;
    int yv = yP[r];
    if (yv < 0) return;
    int nsl = plan[20 + yv];
    float b0 = 1e30f, b1 = 1e30f, b2 = 1e30f, b3 = 1e30f;
    const float4* q4 = (const float4*)(top4pP + (size_t)r * MAXSLOT * 4);
    for (int s = 0; s < nsl; ++s) {
        float4 q = q4[s];
        ins7(q.x, b0, b1, b2, b3); ins7(q.y, b0, b1, b2, b3);
        ins7(q.z, b0, b1, b2, b3); ins7(q.w, b0, b1, b2, b3);
    }
    anchor[idxP[r]] = b3;
}

// Pass 2: FULL-SQUARE count (round-4 engine). Row-side counts only so every
// pair uses orientation A=i — bit-consistent with pass-1's anchors.
__global__ __launch_bounds__(256, 2)
void pass2_kernel(const unsigned short* __restrict__ XS, const float* __restrict__ sq,
                  const float* __restrict__ anchor, int* __restrict__ cntp) {
    __shared__ __align__(16) char smem[65536];

    const int t = threadIdx.x;
    const int w = t >> 6, l = t & 63;
    const int wr = w >> 1, wc = w & 1;
    const int lg = l >> 4, lo16 = l & 15;

    // XCD-aware bijective swizzle (512 % 8 == 0)
    const int bid = blockIdx.x;
    const int wg = (bid & 7) * ((NTIL * NJG) >> 3) + (bid >> 3);
    const int it = wg % NTIL, jg = wg / NTIL;
    const int ibase = it * 128;
    const int jg0 = jg * (128 * NJT);

    float sqi[16]; float anc[16];
    #pragma unroll
    for (int mi = 0; mi < 4; ++mi)
        #pragma unroll
        for (int r = 0; r < 4; ++r) {
            int row = ibase + wr * 64 + mi * 16 + lg * 4 + r;
            sqi[mi * 4 + r] = sq[row];
            anc[mi * 4 + r] = anchor[row];
        }

    const int swz = (lo16 & 7) << 4;
    unsigned aoff[2], boff[2];
    #pragma unroll
    for (int kk = 0; kk < 2; ++kk) {
        const int cA = (kk * 64 + lg * 16) ^ swz;
        aoff[kk] = (unsigned)((wr * 64 + lo16) * 128 + cA);
        boff[kk] = (unsigned)(32768 + (wc * 64 + lo16) * 128 + cA);
    }
    const int srow = w * 32 + (l >> 3);
    const int scol = ((l & 7) ^ (l >> 3)) << 3;
    const unsigned short* gsrc = XS + (size_t)srow * 256 + scol;

    auto STAGE = [&](int jbase_rows, int ks, int par) {
        if (ks < 2 || ks >= 4) {
            const int kA = (ks < 4) ? (ks & 1) * 64 : (ks - 2) * 64;
            char* Ab = smem + par * 16384 + w * 4096;
            const unsigned short* gA = gsrc + (size_t)ibase * 256 + kA;
            #pragma unroll
            for (int q = 0; q < 4; ++q)
                gload_lds16(gA + (size_t)q * 8 * 256, Ab + q * 1024);
        }
        const int kB = (ks < 4) ? ks * 64 : (ks - 4) * 64;
        char* Bb = smem + 32768 + par * 16384 + w * 4096;
        const unsigned short* gB = gsrc + (size_t)jbase_rows * 256 + kB;
        #pragma unroll
        for (int q = 0; q < 4; ++q)
            gload_lds16(gB + (size_t)q * 8 * 256, Bb + q * 1024);
    };

    int cnt16[16];
    #pragma unroll
    for (int c = 0; c < 16; ++c) cnt16[c] = 0;

    STAGE(jg0, 0, 0);
    __syncthreads();

    #pragma unroll 1
    for (int jt = 0; jt < NJT; ++jt) {
        const int jbase = jg0 + jt * 128;
        float sqj[4];
        #pragma unroll
        for (int ni = 0; ni < 4; ++ni)
            sqj[ni] = sq[jbase + wc * 64 + ni * 16 + lo16];

        f32x4 acc[4][4];
        f32x4 zz = {0.0f, 0.0f, 0.0f, 0.0f};
        #pragma unroll
        for (int mi = 0; mi < 4; ++mi)
            #pragma unroll
            for (int ni = 0; ni < 4; ++ni) acc[mi][ni] = zz;

        #pragma unroll
        for (int ks = 0; ks < 6; ++ks) {
            const int par = ks & 1;
            if (ks < 5) STAGE(jbase, ks + 1, par ^ 1);
            else if (jt < NJT - 1) STAGE(jbase + 128, 0, par ^ 1);

            #pragma unroll
            for (int kk = 0; kk < 2; ++kk) {
                short8 aF[4], bF[4];
                #pragma unroll
                for (int mi = 0; mi < 4; ++mi)
                    aF[mi] = *(const short8*)(smem + aoff[kk] + par * 16384 + mi * 2048);
                #pragma unroll
                for (int ni = 0; ni < 4; ++ni)
                    bF[ni] = *(const short8*)(smem + boff[kk] + par * 16384 + ni * 2048);
                #pragma unroll
                for (int mi = 0; mi < 4; ++mi)
                    #pragma unroll
                    for (int ni = 0; ni < 4; ++ni)
                        acc[mi][ni] = __builtin_amdgcn_mfma_f32_16x16x32_bf16(
                            aF[mi], bF[ni], acc[mi][ni], 0, 0, 0);
            }

            if (ks == 5) {
                #pragma unroll
                for (int mi = 0; mi < 4; ++mi)
                    #pragma unroll
                    for (int r = 0; r < 4; ++r) {
                        const int idx = mi * 4 + r;
                        int c = 0;
                        #pragma unroll
                        for (int ni = 0; ni < 4; ++ni) {
                            float d2 = fmaf(-2.0f, acc[mi][ni][r], sqi[idx] + sqj[ni]);
                            d2 = fmaxf(d2, 0.0f);
                            c += (d2 <= anc[idx]) ? 1 : 0;
                        }
                        cnt16[idx] += c;
                    }
            }
            __syncthreads();
        }
    }

    int* scri = (int*)smem;  // [128][2]
    #pragma unroll
    for (int idx = 0; idx < 16; ++idx) {
        int c = cnt16[idx];
        c += __shfl_xor(c, 1); c += __shfl_xor(c, 2);
        c += __shfl_xor(c, 4); c += __shfl_xor(c, 8);
        if (lo16 == 0) {
            int rl = wr * 64 + (idx >> 2) * 16 + lg * 4 + (idx & 3);
            scri[rl * 2 + wc] = c;
        }
    }
    __syncthreads();
    if (t < 128) cntp[(size_t)(ibase + t) * NJG + jg] = scri[t * 2] + scri[t * 2 + 1];
}

__global__ void reduce_kernel(const int* __restrict__ cntp, float* __restrict__ partials) {
    __shared__ float red[256];
    int t = threadIdx.x;
    int row = blockIdx.x * 256 + t;
    int s = 0;
    for (int c = 0; c < NJG; ++c) s += cntp[(size_t)row * NJG + c];
    red[t] = digammaf_dev((float)(s - 1));
    __syncthreads();
    for (int h = 128; h > 0; h >>= 1) {
        if (t < h) red[t] += red[t + h];
        __syncthreads();
    }
    if (t == 0) partials[blockIdx.x] = red[0];
}

__global__ void finalize_kernel(const float* __restrict__ partials, const int* __restrict__ cls,
                                float* __restrict__ out) {
    if (threadIdx.x == 0) {
        float acc = 0.0f;
        for (int c = 0; c < NTOT / 256; ++c) acc += partials[c];
        float Nf = (float)NTOT;
        float avg_m = acc / Nf;
        float avgNx = 0.0f;
        for (int c = 0; c < NCLS; ++c) {
            float nx = (float)cls[c];
            if (nx > 0.0f) avgNx += (nx / Nf) * digammaf_dev(nx);
        }
        float mi = digammaf_dev(Nf) - avgNx + digammaf_dev(3.0f) - avg_m;
        out[0] = fmaxf(mi / logf(2.0f), 0.0f);
    }
}

extern "C" void kernel_launch(void* const* d_in, const int* in_sizes, int n_in,
                              void* d_out, int out_size, void* d_ws, size_t ws_size,
                              hipStream_t stream) {
    const float* X = (const float*)d_in[0];
    const int* y = (const int*)d_in[1];
    float* out = (float*)d_out;

    float* sq       = (float*)d_ws;                                   // 8192
    float* anchors  = sq + NTOT;                                      // 8192
    float* partials = anchors + NTOT;                                 // 32
    int*   cls      = (int*)(partials + 32);                          // 16
    int*   bcnt     = cls + 16;                                       // 320
    int*   sOff     = bcnt + 320;                                     // 320
    int*   plan     = sOff + 320;                                     // 48
    int*   yP       = plan + 48;                                      // 9472
    int*   idxP     = yP + NPMAX;                                     // 9472
    float* sqP      = (float*)(idxP + NPMAX);                         // 9472
    unsigned short* XS  = (unsigned short*)(sqP + NPMAX);             // 8192*256 (4 MB)
    unsigned short* XSP = XS + (size_t)NTOT * 256;                    // 9472*256 (4.85 MB)
    float* top4pP   = (float*)(XSP + (size_t)NPMAX * 256);            // 9472*32*4 (4.85 MB)
    int*   cntp     = (int*)(top4pP + (size_t)NPMAX * MAXSLOT * 4);   // 8192*8

    prep_kernel<<<NTOT / 4, 256, 0, stream>>>(X, sq, XS);
    count_kernel<<<NTOT / 256, 256, 0, stream>>>(y, bcnt);
    plan_kernel<<<1, 256, 0, stream>>>(bcnt, plan, sOff, cls, yP);
    scatter_kernel<<<NTOT / 256, 256, 0, stream>>>(y, sq, XS, sOff, XSP, sqP, yP, idxP);
    pass1_kernel<<<G1, 256, 0, stream>>>(XSP, yP, sqP, plan, top4pP);
    anchorP_kernel<<<NPMAX / 256, 256, 0, stream>>>(top4pP, yP, idxP, plan, anchors);
    pass2_kernel<<<NTIL * NJG, 256, 0, stream>>>(XS, sq, anchors, cntp);
    reduce_kernel<<<NTOT / 256, 256, 0, stream>>>(cntp, partials);
    finalize_kernel<<<1, 64, 0, stream>>>(partials, cls, out);
}